// Round 4
// baseline (233.774 us; speedup 1.0000x reference)
//
#include <hip/hip_runtime.h>
#include <stdint.h>

// HashedEmbeddingBag: out[b][d] = sum_{i<50} weight[(idx[b][i]*P1 + d*P2) % WS]
// WS = 2,000,000; B = 16384; L = 50; D = 128.
//
// R13: R12 skeleton + unroll-2 inner loop with ds_read2-paired keys.
// R12 post-mortem: VALU 66% (120us abs) at 181us; calibration across
// R9/R12 gives ~4.25 cy per static VALU op (vs 2 issue) -> latency-bound
// serial chain (gather ds_read + key ds_read in the dependence path, only
// 4 waves/SIMD); both pipes ~65% busy, poor overlap. Levers:
//  - unroll-2: two independent element chains per iteration (ILP halves
//    the stall factor), iterations 1333 -> ~700 (E[max ceil(c/2)]).
//  - keys are sequential: ext[kq+1], ext[kq+2] adjacent -> compiler
//    merges to ONE ds_read2_b32 (4B-align only) -> key DS instrs halved.
//  - all hot-loop LDS accesses are INDEX-based on the __shared__ blob
//    (no 64-bit generic char* walk): guaranteed ds_ addressing, 1-op
//    32-bit advances.
// Element 1 is predicated (p1 = u1 < LIM): its gather addr clamps to 0
// (safe LDS word), its add contributes literal +0.0f (IEEE: only effect
// is -0 -> +0, absmax unaffected). Per-(lane,stream) consumption order
// unchanged -> absmax stays 0.25 (threshold 0.71).
// Structure from R12 (proven twice): k=2 pair-merged streams, keys
// (v<<1)|b + rotation copy, 8 sentinels; dbuf 2x64KB bf16 halves
// (62 regions), stage r+1 issued BEFORE sweeping r; register accums.

#define WS       2000000
#define EMB_DIM  128
#define BAG_LEN  50
#define BATCH    16384

#define NBLK     256
#define NTHR     1024
#define BAGS_PB  64
#define NPAIR    32                      // bag-pair streams per block
#define SPT      4                       // streams per thread
#define EXTP     208                     // 100 + 100 rotation + 8 sentinels
#define THALF    32768                   // entries per tile half (65536 B)
#define NREGD    62                      // 61*32768=1,998,848; last len 1152
#define SBIG     300227u                 // P2 % WS
#define SENT     0x10000000u             // sentinel key; u stays >= LIM

#define OFF_T1   65536                   // tile half 1
#define OFF_EXT  131072                  // 32*208*4 = 26624 B keys
#define SMEM_SZ  157696

#define GLOAD_LDS16(gp, lp)                                            \
    __builtin_amdgcn_global_load_lds(                                  \
        (const __attribute__((address_space(1))) uint32_t*)(gp),       \
        (__attribute__((address_space(3))) uint32_t*)(lp), 16, 0, 0)

// ---- pre-pass: fp32 table -> bf16 (round-to-nearest-even) ----
__global__ __launch_bounds__(1024) void conv_bf16(
    const float* __restrict__ w, uint16_t* __restrict__ o)
{
    const int i = (blockIdx.x * 1024 + threadIdx.x) * 4;   // 4 floats/thread
    if (i >= WS) return;
    const float4 f = *(const float4*)(w + i);
    uint32_t u0 = __float_as_uint(f.x), u1 = __float_as_uint(f.y);
    uint32_t u2 = __float_as_uint(f.z), u3 = __float_as_uint(f.w);
    ushort4 r;
    r.x = (uint16_t)((u0 + 0x7FFFu + ((u0 >> 16) & 1u)) >> 16);
    r.y = (uint16_t)((u1 + 0x7FFFu + ((u1 >> 16) & 1u)) >> 16);
    r.z = (uint16_t)((u2 + 0x7FFFu + ((u2 >> 16) & 1u)) >> 16);
    r.w = (uint16_t)((u3 + 0x7FFFu + ((u3 >> 16) & 1u)) >> 16);
    *(ushort4*)(o + i) = r;
}

__global__ __launch_bounds__(NTHR, 4) void heb_bf16(
    const uint16_t* __restrict__ wbf,
    const int*      __restrict__ indices,
    float*          __restrict__ out)
{
    __shared__ __align__(16) uint8_t smem[SMEM_SZ];

    const int tid     = threadIdx.x;
    const int d       = tid & 127;
    const int g       = tid >> 7;          // group 0..7 (pairs 4g..4g+3)
    const int bagBase = blockIdx.x * BAGS_PB;

    uint16_t* tile0 = (uint16_t*)&smem[0];
    uint32_t* ext   = (uint32_t*)&smem[OFF_EXT];
    // sort scratch lives in tile half 1 (dead before half 1 is first staged
    // -- staging of region 1 is issued only after the phase-3 barrier)
    uint32_t* araw  = (uint32_t*)&smem[OFF_T1];           // [64][52]
    uint32_t* S     = (uint32_t*)&smem[OFF_T1 + 13312];   // [64][52]

    // ---- phase 0: stage region 0 into half 0 NOW; hides under sort ----
    for (int s = tid; s < (THALF >> 3); s += NTHR)
        GLOAD_LDS16(wbf + (s << 3), tile0 + (s << 3));

    // ---- phase 1: sentinel-fill ext; hash a = idx*P1 % WS ----
    for (int p = tid; p < NPAIR * EXTP; p += NTHR) ext[p] = SENT;
    for (int p = tid; p < BAGS_PB * BAG_LEN; p += NTHR) {
        uint32_t b = (uint32_t)p / 50u;
        uint32_t i = (uint32_t)p - b * 50u;
        uint64_t idx = (uint64_t)(uint32_t)indices[bagBase * BAG_LEN + p];
        araw[b * 52 + i] = (uint32_t)((idx * 9824516537ull) % (uint64_t)WS);
    }
    __syncthreads();

    // ---- phase 2a: rank-sort each bag (ties by index) -> S ----
    for (int p = tid; p < BAGS_PB * BAG_LEN; p += NTHR) {
        uint32_t b = (uint32_t)p / 50u;
        uint32_t i = (uint32_t)p - b * 50u;
        uint32_t v = araw[b * 52 + i];
        int rank = 0;
        for (int q = 0; q < BAG_LEN; ++q) {
            uint32_t w = araw[b * 52 + q];
            rank += (w < v || (w == v && q < (int)i)) ? 1 : 0;
        }
        S[b * 52 + rank] = v;
    }
    __syncthreads();

    // ---- phase 2b: 2-way merge per pair via one binary search ----
    for (int p = tid; p < BAGS_PB * BAG_LEN; p += NTHR) {
        uint32_t bag = (uint32_t)p / 50u;
        uint32_t i   = (uint32_t)p - bag * 50u;
        uint32_t pr  = bag >> 1, b = bag & 1u;
        uint32_t v = S[bag * 52 + i];
        const uint32_t* T = &S[(bag ^ 1u) * 52];
        uint32_t key = b ? v + 1u : v;         // tie-break by bag id
        int lo = 0, hi = 50;
        while (lo < hi) {                      // ~6 uniform steps
            int mid = (lo + hi) >> 1;
            bool lt = T[mid] < key;
            lo = lt ? mid + 1 : lo;
            hi = lt ? hi : mid;
        }
        uint32_t* eo = ext + pr * EXTP;
        int rk = (int)i + lo;
        eo[rk]       = (v << 1) | b;                    // first copy
        eo[rk + 100] = ((v + (uint32_t)WS) << 1) | b;   // rotation copy
    }
    __syncthreads();                       // ext final; scratch (half 1) dead

    // ---- phase 3: per-thread 4-stream init (word-index state) ----
    const uint32_t c  = ((uint32_t)d * SBIG) % (uint32_t)WS;
    const uint32_t C2 = (uint32_t)(((int)c - WS) * 2);  // 2*(c-WS) mod 2^32
    const uint32_t limit2 = ((uint32_t)WS - c) << 1;    // keys < 2*(WS-c)

    uint32_t kq4[SPT], K4[SPT];
    float    s0r[SPT], s1r[SPT];
#pragma unroll
    for (int qi = 0; qi < SPT; ++qi) {
        const uint32_t rbase = (uint32_t)((g << 2) + qi) * EXTP;
        int lo = 0, hi = 100;
        while (lo < hi) {
            int mid = (lo + hi) >> 1;
            bool lt = ext[rbase + (uint32_t)mid] < limit2;
            lo = lt ? mid + 1 : lo;
            hi = lt ? hi : mid;
        }
        kq4[qi] = rbase + (uint32_t)lo;    // absolute word index into ext
        K4[qi]  = ext[rbase + (uint32_t)lo];
        s0r[qi] = 0.0f; s1r[qi] = 0.0f;
    }
    __syncthreads();                       // drains stage-0 (long complete)

    // ---- phase 4: region sweep, double-buffered 64KB halves ----
    for (int r = 0; r < NREGD; ++r) {
        // issue next-region staging first: overlaps this region's sweep;
        // target half was last read before the barrier ending iter r-1.
        if (r + 1 < NREGD) {
            const int lo2  = (r + 1) * THALF;
            const int len2 = (THALF < WS - lo2) ? THALF : (WS - lo2);
            uint16_t* dst = (uint16_t*)&smem[((r + 1) & 1) ? OFF_T1 : 0];
            for (int s = tid; s < (len2 >> 3); s += NTHR)
                GLOAD_LDS16(wbf + lo2 + (s << 3), dst + (s << 3));
        }

        const int rlo = r * THALF;
        const int len = (THALF < WS - rlo) ? THALF : (WS - rlo);
        const uint32_t TB  = (r & 1) ? (uint32_t)OFF_T1 : 0u;
        const uint32_t CLr = C2 + TB - ((uint32_t)rlo << 1);
        const uint32_t LIM = ((uint32_t)len << 1) + TB;

#pragma unroll
        for (int qi = 0; qi < SPT; ++qi) {
            uint32_t kq = kq4[qi], K0 = K4[qi];
            float s0 = s0r[qi], s1 = s1r[qi];
            uint32_t u0 = K0 + CLr;        // 2*(pos-rlo) + tag + TB
            while (u0 < LIM) {
                // paired sequential keys: adjacent dword offsets ->
                // one ds_read2_b32 (4B alignment only)
                const uint32_t K1 = ext[kq + 1u];
                const uint32_t K2 = ext[kq + 2u];
                // element 0 (unconditionally due)
                const uint32_t raw0 =
                    *(const uint16_t*)(smem + (u0 & ~1u));
                // element 1 (predicated)
                const uint32_t u1 = K1 + CLr;
                const bool p1 = u1 < LIM;
                const uint32_t a1 = p1 ? (u1 & ~1u) : 0u;   // safe clamp
                const uint32_t raw1 = *(const uint16_t*)(smem + a1);
                // routes (order per stream preserved: elem0 then elem1)
                const float v0 = __uint_as_float(raw0 << 16);
                const bool odd0 = (u0 & 1u) != 0u;
                s0 += odd0 ? 0.0f : v0;
                s1 += odd0 ? v0 : 0.0f;
                const float v1 =
                    p1 ? __uint_as_float(raw1 << 16) : 0.0f;
                const bool odd1 = (u1 & 1u) != 0u;
                s0 += odd1 ? 0.0f : v1;
                s1 += odd1 ? v1 : 0.0f;
                // advance by 1 or 2 consumed keys
                kq += p1 ? 2u : 1u;
                K0  = p1 ? K2 : K1;
                u0  = K0 + CLr;
            }
            kq4[qi] = kq; K4[qi] = K0;
            s0r[qi] = s0; s1r[qi] = s1;
        }
        __syncthreads();                   // next half staged + this half done
    }

    // ---- phase 5: output straight from registers (bag = 8g + 2qi + t) ----
#pragma unroll
    for (int qi = 0; qi < SPT; ++qi) {
        const int bag = (g << 3) + (qi << 1);
        out[(size_t)(bagBase + bag) * EMB_DIM + d]     = s0r[qi];
        out[(size_t)(bagBase + bag + 1) * EMB_DIM + d] = s1r[qi];
    }
}

// ---- fallback (ws too small): R7's proven fp32 single-tile kernel ----
#define RSIZE_FB 32768
#define NREG_FB  62
#define EXT_N    104
#define SENT4    0x10000000u

__global__ __launch_bounds__(NTHR, 4) void heb_single(
    const float* __restrict__ weight,
    const int*   __restrict__ indices,
    float*       __restrict__ out)
{
    __shared__ __align__(16) float tile[RSIZE_FB];
    __shared__ uint32_t ext4[BAGS_PB][EXT_N];
    const int tid = threadIdx.x, d = tid & 127, bag_lo = tid >> 7;
    const int bagBase = blockIdx.x * BAGS_PB;
    uint32_t* araw = (uint32_t*)&tile[0];
    for (int p = tid; p < BAGS_PB * BAG_LEN; p += NTHR) {
        uint32_t g = (uint32_t)p / 50u, i = (uint32_t)p - g * 50u;
        uint64_t idx = (uint64_t)(uint32_t)indices[bagBase * BAG_LEN + p];
        araw[g * 52 + i] = (uint32_t)((idx * 9824516537ull) % (uint64_t)WS);
    }
    __syncthreads();
    for (int p = tid; p < BAGS_PB * BAG_LEN; p += NTHR) {
        uint32_t g = (uint32_t)p / 50u, i = (uint32_t)p - g * 50u;
        uint32_t v = araw[g * 52 + i];
        int rank = 0;
        for (int q = 0; q < BAG_LEN; ++q) {
            uint32_t w = araw[g * 52 + q];
            rank += (w < v || (w == v && q < (int)i)) ? 1 : 0;
        }
        ext4[g][rank] = v << 2;
        ext4[g][rank + 50] = (v + (uint32_t)WS) << 2;
    }
    for (int p = tid; p < BAGS_PB * 4; p += NTHR)
        ext4[p >> 2][100 + (p & 3)] = SENT4;
    __syncthreads();
    const uint32_t c = ((uint32_t)d * SBIG) % (uint32_t)WS;
    const uint32_t C4 = (uint32_t)(((int)c - WS) * 4);
    const uint32_t wmc4 = ((uint32_t)WS - c) << 2;
    uint32_t t4[8], h4[8]; float sm[8];
#pragma unroll
    for (int k = 0; k < 8; ++k) {
        const uint32_t* eg = &ext4[(bag_lo << 3) + k][0];
        int nlow = 0;
        for (int q = 0; q < BAG_LEN; ++q) nlow += (eg[q] < wmc4) ? 1 : 0;
        t4[k] = (uint32_t)nlow << 2; h4[k] = eg[nlow] + C4; sm[k] = 0.0f;
    }
    for (int r = 0; r < NREG_FB; ++r) {
        const int lo = r * RSIZE_FB;
        const int len = (RSIZE_FB < WS - lo) ? RSIZE_FB : (WS - lo);
        __syncthreads();
        for (int s = tid; s < (len >> 2); s += NTHR)
            GLOAD_LDS16(weight + lo + (s << 2), &tile[s << 2]);
        __syncthreads();
        const uint32_t lo4 = ((uint32_t)lo) << 2;
        const uint32_t hi4 = (r == NREG_FB - 1) ? (uint32_t)(4 * WS)
                                                : lo4 + ((uint32_t)RSIZE_FB << 2);
        const char* tb = (const char*)&tile[0];
#pragma unroll
        for (int k = 0; k < 8; ++k) {
            const char* eg = (const char*)&ext4[(bag_lo << 3) + k][0];
            uint32_t t_ = t4[k], h_ = h4[k]; float s_ = sm[k];
            while (h_ < hi4) {
                s_ += *(const float*)(tb + (h_ - lo4));
                t_ += 4u;
                h_ = *(const uint32_t*)(eg + t_) + C4;
            }
            t4[k] = t_; h4[k] = h_; sm[k] = s_;
        }
    }
#pragma unroll
    for (int k = 0; k < 8; ++k)
        out[(size_t)(bagBase + (bag_lo << 3) + k) * EMB_DIM + d] = sm[k];
}

extern "C" void kernel_launch(void* const* d_in, const int* in_sizes, int n_in,
                              void* d_out, int out_size, void* d_ws, size_t ws_size,
                              hipStream_t stream)
{
    const float* weight  = (const float*)d_in[0];   // [2,000,000] fp32
    const int*   indices = (const int*)d_in[1];     // [16384*50] int
    float*       out     = (float*)d_out;           // [16384*128] fp32

    if (ws_size >= (size_t)WS * sizeof(uint16_t)) {
        uint16_t* wbf = (uint16_t*)d_ws;
        conv_bf16<<<(WS / 4 + 1023) / 1024, 1024, 0, stream>>>(weight, wbf);
        heb_bf16<<<NBLK, NTHR, 0, stream>>>(wbf, indices, out);
    } else {
        heb_single<<<NBLK, NTHR, 0, stream>>>(weight, indices, out);
    }
}